// Round 1
// 571.151 us; speedup vs baseline: 1.0261x; 1.0261x over previous
//
#include <hip/hip_runtime.h>

// Problem dims
#define B_ 64
#define E_ 2048
#define H_ 1024
#define S_ 512
#define V_ 32000
#define NSPLIT 8

typedef __bf16 bf16x8 __attribute__((ext_vector_type(8)));
typedef float f32x4 __attribute__((ext_vector_type(4)));

__device__ __forceinline__ f32x4 mfma16(bf16x8 a, bf16x8 b, f32x4 c) {
  return __builtin_amdgcn_mfma_f32_16x16x32_bf16(a, b, c, 0, 0, 0);
}

// 8 consecutive fp32 -> bf16x8
__device__ __forceinline__ bf16x8 cvt8(const float* __restrict__ p) {
  f32x4 a = *(const f32x4*)p;
  f32x4 b = *(const f32x4*)(p + 4);
  bf16x8 r;
#pragma unroll
  for (int j = 0; j < 4; ++j) { r[j] = (__bf16)a[j]; r[4 + j] = (__bf16)b[j]; }
  return r;
}

// ---------------------------------------------------------------------------
// Kernel P: convert x (64x2048) and h0 (64x1024) fp32 -> bf16 workspace.
// Grid: (B_*E_ + B_*H_)/(256*8) = 96 blocks.
// ---------------------------------------------------------------------------
__global__ __launch_bounds__(256) void k_prep(
    const float* __restrict__ x, const float* __restrict__ h0,
    __bf16* __restrict__ xb, __bf16* __restrict__ h0b) {
  int idx = (blockIdx.x * 256 + threadIdx.x) * 8;
  const float* src;
  __bf16* dst;
  if (idx < B_ * E_) { src = x + idx; dst = xb + idx; }
  else { int j = idx - B_ * E_; src = h0 + j; dst = h0b + j; }
  bf16x8 v = cvt8(src);
  *(bf16x8*)dst = v;
}

// ---------------------------------------------------------------------------
// Shared 64xK (bf16 A) @ Kx32 (fp32 B strip) -> acc[2] per wave.
// B tile staged via f32x4 vector loads -> bf16, TRANSPOSED into LDS
// (lt[v][k], row stride 72 bf16 = 144 B keeps ds_read_b128 aligned and
// spreads the 4 ki-groups across banks). 1-deep register prefetch,
// double-buffered LDS, ONE barrier per tile (writes target the other buffer).
// Wave w: cols (w&1)*16, rows (w>>1)*32 (mt=0,1).
// ---------------------------------------------------------------------------
__device__ __forceinline__ void gemm32(
    const __bf16* __restrict__ A, int lda,
    const float* __restrict__ Bg, int ldb, int K,
    __bf16 (*lt)[32][72], f32x4 acc[2]) {
  const int tid = threadIdx.x;
  const int wave = tid >> 6, lane = tid & 63;
  const int mi = lane & 15, ki = (lane >> 4) * 8;
  const int c16 = (wave & 1) * 16;
  const int mh = (wave >> 1) * 32;
  const int sk = tid >> 3;        // 0..31 (k row within half-tile)
  const int sv = (tid & 7) * 4;   // 0..28 (v col group)
  const int NT = K / 64;
  f32x4 pf0 = *(const f32x4*)(Bg + (size_t)sk * ldb + sv);
  f32x4 pf1 = *(const f32x4*)(Bg + (size_t)(sk + 32) * ldb + sv);
  for (int t = 0; t < NT; ++t) {
    __bf16(*L)[72] = lt[t & 1];
#pragma unroll
    for (int i = 0; i < 4; ++i) {
      L[sv + i][sk] = (__bf16)pf0[i];
      L[sv + i][32 + sk] = (__bf16)pf1[i];
    }
    __syncthreads();
    if (t + 1 < NT) {
      const float* nb = Bg + (size_t)(t + 1) * 64 * ldb;
      pf0 = *(const f32x4*)(nb + (size_t)sk * ldb + sv);
      pf1 = *(const f32x4*)(nb + (size_t)(sk + 32) * ldb + sv);
    }
    const __bf16* Ab = A + (size_t)t * 64 + ki;
#pragma unroll
    for (int kk = 0; kk < 2; ++kk) {
      bf16x8 bfrag = *(const bf16x8*)(&L[c16 + mi][kk * 32 + ki]);
#pragma unroll
      for (int mt = 0; mt < 2; ++mt) {
        bf16x8 a = *(const bf16x8*)(Ab + (size_t)(mh + mt * 16 + mi) * lda + kk * 32);
        acc[mt] = mfma16(a, bfrag, acc[mt]);
      }
    }
  }
}

// ---------------------------------------------------------------------------
// Kernel A: blocks [0,32): m = (x@Wmx+bmx)*(h0@Wmh+bmh) -> bf16 ws
//           blocks [32,160): g1 = x@Wx (raw) -> fp32 ws
// ---------------------------------------------------------------------------
__global__ __launch_bounds__(256) void k_m_g1(
    const __bf16* __restrict__ xb, const __bf16* __restrict__ h0b,
    const float* __restrict__ Wmx, const float* __restrict__ bmx,
    const float* __restrict__ Wmh, const float* __restrict__ bmh,
    const float* __restrict__ Wx,
    __bf16* __restrict__ m_out, float* __restrict__ g1) {
  __shared__ __bf16 lt[2][32][72];
  const int tid = threadIdx.x;
  const int wave = tid >> 6, lane = tid & 63;
  const int mi = lane & 15;
  const int c16 = (wave & 1) * 16;
  const int mh = (wave >> 1) * 32;
  const int blk = blockIdx.x;
  if (blk < H_ / 32) {
    const int v0 = blk * 32;
    f32x4 amx[2] = {}, amh[2] = {};
    gemm32(xb, E_, Wmx + v0, H_, E_, lt, amx);
    gemm32(h0b, H_, Wmh + v0, H_, H_, lt, amh);
    const int col = v0 + c16 + mi;
    const float bxv = bmx[col], bhv = bmh[col];
#pragma unroll
    for (int mt = 0; mt < 2; ++mt)
#pragma unroll
      for (int r = 0; r < 4; ++r) {
        int row = mh + mt * 16 + (lane >> 4) * 4 + r;
        m_out[(size_t)row * H_ + col] = (__bf16)((amx[mt][r] + bxv) * (amh[mt][r] + bhv));
      }
  } else {
    const int v0 = (blk - H_ / 32) * 32;
    f32x4 acc[2] = {};
    gemm32(xb, E_, Wx + v0, 4 * H_, E_, lt, acc);
    const int col = v0 + c16 + mi;
#pragma unroll
    for (int mt = 0; mt < 2; ++mt)
#pragma unroll
      for (int r = 0; r < 4; ++r) {
        int row = mh + mt * 16 + (lane >> 4) * 4 + r;
        g1[(size_t)row * 4 * H_ + col] = acc[mt][r];
      }
  }
}

// ---------------------------------------------------------------------------
// Kernel C: g2 = m@Wm -> fp32 ws. 128 blocks (32-col strips of 4096).
// ---------------------------------------------------------------------------
__global__ __launch_bounds__(256) void k_g2(
    const __bf16* __restrict__ m_in, const float* __restrict__ Wm,
    float* __restrict__ g2) {
  __shared__ __bf16 lt[2][32][72];
  const int tid = threadIdx.x;
  const int wave = tid >> 6, lane = tid & 63;
  const int mi = lane & 15;
  const int c16 = (wave & 1) * 16;
  const int mh = (wave >> 1) * 32;
  const int v0 = blockIdx.x * 32;
  f32x4 acc[2] = {};
  gemm32(m_in, H_, Wm + v0, 4 * H_, H_, lt, acc);
  const int col = v0 + c16 + mi;
#pragma unroll
  for (int mt = 0; mt < 2; ++mt)
#pragma unroll
    for (int r = 0; r < 4; ++r) {
      int row = mh + mt * 16 + (lane >> 4) * 4 + r;
      g2[(size_t)row * 4 * H_ + col] = acc[mt][r];
    }
}

// ---------------------------------------------------------------------------
// Kernel D: gates -> h (fp32) and Acat[:, 0:H] (bf16).  (unchanged)
// ---------------------------------------------------------------------------
__global__ __launch_bounds__(256) void k_gates(
    const float* __restrict__ g1, const float* __restrict__ g2,
    const float* __restrict__ bx, const float* __restrict__ bm,
    const float* __restrict__ c0,
    float* __restrict__ h_f32, __bf16* __restrict__ Acat) {
  const int idx = blockIdx.x * blockDim.x + threadIdx.x;
  const int b = idx >> 10, j = idx & (H_ - 1);
  const size_t base = (size_t)b * 4 * H_ + j;
  float gf = g1[base] + g2[base] + bx[j] + bm[j];
  float gi = g1[base + H_] + g2[base + H_] + bx[j + H_] + bm[j + H_];
  float go = g1[base + 2 * H_] + g2[base + 2 * H_] + bx[j + 2 * H_] + bm[j + 2 * H_];
  float gc = g1[base + 3 * H_] + g2[base + 3 * H_] + bx[j + 3 * H_] + bm[j + 3 * H_];
  float f = 1.f / (1.f + __expf(-gf));
  float i = 1.f / (1.f + __expf(-gi));
  float o = 1.f / (1.f + __expf(-go));
  float ct = tanhf(gc);
  float c = f * c0[(size_t)b * H_ + j] + i * ct;
  float h = o * tanhf(c);
  h_f32[(size_t)b * H_ + j] = h;
  Acat[(size_t)b * 2 * H_ + j] = (__bf16)h;
}

// ---------------------------------------------------------------------------
// Kernel E: flash-style attention partials. (unchanged)
// ---------------------------------------------------------------------------
__global__ __launch_bounds__(256) void k_attn_partial(
    const float* __restrict__ sv, const float* __restrict__ h_f32,
    float* __restrict__ ctxp, float* __restrict__ Mp, float* __restrict__ Lp) {
  const int b = blockIdx.x >> 3, split = blockIdx.x & (NSPLIT - 1);
  const int t = threadIdx.x;
  const int d0 = t * 4;
  float hr[4];
#pragma unroll
  for (int i = 0; i < 4; ++i) hr[i] = h_f32[(size_t)b * H_ + d0 + i];
  float M = -1e30f, L = 0.f;
  float cx[4] = {0.f, 0.f, 0.f, 0.f};
  __shared__ float red[2][4][4];
  const float* svb = sv + ((size_t)b * S_ + split * (S_ / NSPLIT)) * H_;
  for (int s4 = 0; s4 < S_ / NSPLIT; s4 += 4) {
    float sval[4][4];
    float part[4];
#pragma unroll
    for (int ss = 0; ss < 4; ++ss) {
      f32x4 v4 = *(const f32x4*)(svb + (size_t)(s4 + ss) * H_ + d0);
      float dot = 0.f;
#pragma unroll
      for (int i = 0; i < 4; ++i) {
        sval[ss][i] = v4[i];
        dot += hr[i] * v4[i];
      }
      part[ss] = dot;
    }
#pragma unroll
    for (int ss = 0; ss < 4; ++ss)
#pragma unroll
      for (int off = 32; off > 0; off >>= 1) part[ss] += __shfl_xor(part[ss], off);
    const int wv = t >> 6, ln = t & 63;
    const int buf = (s4 >> 2) & 1;
    if (ln == 0) {
#pragma unroll
      for (int ss = 0; ss < 4; ++ss) red[buf][wv][ss] = part[ss];
    }
    __syncthreads();
#pragma unroll
    for (int ss = 0; ss < 4; ++ss) {
      float score = red[buf][0][ss] + red[buf][1][ss] + red[buf][2][ss] + red[buf][3][ss];
      float nM = fmaxf(M, score);
      float al = __expf(M - nM);
      float w = __expf(score - nM);
      L = L * al + w;
#pragma unroll
      for (int i = 0; i < 4; ++i) cx[i] = cx[i] * al + w * sval[ss][i];
      M = nM;
    }
  }
  const int p = b * NSPLIT + split;
#pragma unroll
  for (int i = 0; i < 4; ++i) ctxp[(size_t)p * H_ + d0 + i] = cx[i];
  if (t == 0) { Mp[p] = M; Lp[p] = L; }
}

// ---------------------------------------------------------------------------
// Kernel F: combine partials -> context -> Acat[:, H:2H] (bf16). (unchanged)
// ---------------------------------------------------------------------------
__global__ __launch_bounds__(256) void k_attn_combine(
    const float* __restrict__ ctxp, const float* __restrict__ Mp,
    const float* __restrict__ Lp, __bf16* __restrict__ Acat) {
  const int b = blockIdx.x;
  const int t = threadIdx.x;
  const int d0 = t * 4;
  float gM = -1e30f;
#pragma unroll
  for (int s = 0; s < NSPLIT; ++s) gM = fmaxf(gM, Mp[b * NSPLIT + s]);
  float w[NSPLIT];
  float T = 0.f;
#pragma unroll
  for (int s = 0; s < NSPLIT; ++s) {
    w[s] = __expf(Mp[b * NSPLIT + s] - gM);
    T += w[s] * Lp[b * NSPLIT + s];
  }
  const float inv = 1.f / T;
  float cx[4] = {0.f, 0.f, 0.f, 0.f};
#pragma unroll
  for (int s = 0; s < NSPLIT; ++s) {
#pragma unroll
    for (int i = 0; i < 4; ++i) cx[i] += w[s] * ctxp[(size_t)(b * NSPLIT + s) * H_ + d0 + i];
  }
#pragma unroll
  for (int i = 0; i < 4; ++i)
    Acat[(size_t)b * 2 * H_ + H_ + d0 + i] = (__bf16)(cx[i] * inv);
}

// ---------------------------------------------------------------------------
// Kernel G: logits = Acat@Wout + bout. 500 blocks x 256.
// 64-col strip; Wout tile (64k x 64v fp32) staged via f32x4 -> bf16,
// transposed into LDS; B-fragments are single ds_read_b128.
// ---------------------------------------------------------------------------
__global__ __launch_bounds__(256) void k_logits(
    const __bf16* __restrict__ Acat, const float* __restrict__ Wout,
    const float* __restrict__ bout, float* __restrict__ out) {
  __shared__ __bf16 lt[2][64][72];
  const int tid = threadIdx.x;
  const int wave = tid >> 6, lane = tid & 63;
  const int mi = lane & 15, ki = (lane >> 4) * 8;
  const int v0 = blockIdx.x * 64;
  const int sk = tid >> 4;         // 0..15
  const int sv = (tid & 15) * 4;   // 0..60
  const float* Bg = Wout + v0;
  f32x4 pf[4];
#pragma unroll
  for (int r = 0; r < 4; ++r)
    pf[r] = *(const f32x4*)(Bg + (size_t)(r * 16 + sk) * V_ + sv);
  f32x4 acc[4] = {};
  const int NT = 2 * H_ / 64;  // 32
  for (int t = 0; t < NT; ++t) {
    __bf16(*L)[72] = lt[t & 1];
#pragma unroll
    for (int r = 0; r < 4; ++r)
#pragma unroll
      for (int i = 0; i < 4; ++i)
        L[sv + i][r * 16 + sk] = (__bf16)pf[r][i];
    __syncthreads();
    if (t + 1 < NT) {
      const float* nb = Bg + (size_t)(t + 1) * 64 * V_;
#pragma unroll
      for (int r = 0; r < 4; ++r)
        pf[r] = *(const f32x4*)(nb + (size_t)(r * 16 + sk) * V_ + sv);
    }
    const __bf16* Ab = Acat + t * 64 + ki;
#pragma unroll
    for (int kk = 0; kk < 2; ++kk) {
      bf16x8 bfrag = *(const bf16x8*)(&L[wave * 16 + mi][kk * 32 + ki]);
#pragma unroll
      for (int mt = 0; mt < 4; ++mt) {
        bf16x8 a = *(const bf16x8*)(Ab + (size_t)(mt * 16 + mi) * 2 * H_ + kk * 32);
        acc[mt] = mfma16(a, bfrag, acc[mt]);
      }
    }
  }
  const int col = v0 + wave * 16 + mi;
  const float bo = bout[col];
#pragma unroll
  for (int mt = 0; mt < 4; ++mt)
#pragma unroll
    for (int r = 0; r < 4; ++r) {
      int row = mt * 16 + (lane >> 4) * 4 + r;
      out[(size_t)row * V_ + col] = acc[mt][r] + bo;
    }
}

// ---------------------------------------------------------------------------
extern "C" void kernel_launch(void* const* d_in, const int* in_sizes, int n_in,
                              void* d_out, int out_size, void* d_ws, size_t ws_size,
                              hipStream_t stream) {
  const float* x    = (const float*)d_in[0];
  const float* h0   = (const float*)d_in[1];
  const float* c0   = (const float*)d_in[2];
  const float* sv   = (const float*)d_in[3];
  const float* Wmx  = (const float*)d_in[4];
  const float* bmx  = (const float*)d_in[5];
  const float* Wmh  = (const float*)d_in[6];
  const float* bmh  = (const float*)d_in[7];
  const float* Wx   = (const float*)d_in[8];
  const float* bx   = (const float*)d_in[9];
  const float* Wm   = (const float*)d_in[10];
  const float* bm   = (const float*)d_in[11];
  const float* Wout = (const float*)d_in[12];
  const float* bout = (const float*)d_in[13];
  float* out = (float*)d_out;

  char* ws = (char*)d_ws;
  size_t off = 0;
  __bf16* m_ws = (__bf16*)(ws + off); off += (size_t)B_ * H_ * 2;          // 128KB
  float* g1_ws = (float*)(ws + off);  off += (size_t)B_ * 4 * H_ * 4;      // 1MB
  float* g2_ws = (float*)(ws + off);  off += (size_t)B_ * 4 * H_ * 4;      // 1MB
  float* h_ws  = (float*)(ws + off);  off += (size_t)B_ * H_ * 4;          // 256KB
  __bf16* Acat = (__bf16*)(ws + off); off += (size_t)B_ * 2 * H_ * 2;      // 256KB
  float* ctxp  = (float*)(ws + off);  off += (size_t)B_ * NSPLIT * H_ * 4; // 2MB
  float* Mp    = (float*)(ws + off);  off += (size_t)B_ * NSPLIT * 4;
  float* Lp    = (float*)(ws + off);  off += (size_t)B_ * NSPLIT * 4;
  __bf16* xb   = (__bf16*)(ws + off); off += (size_t)B_ * E_ * 2;          // 256KB
  __bf16* h0b  = (__bf16*)(ws + off); off += (size_t)B_ * H_ * 2;          // 128KB

  k_prep<<<(B_ * E_ + B_ * H_) / (256 * 8), 256, 0, stream>>>(x, h0, xb, h0b);
  k_m_g1<<<H_ / 32 + 4 * H_ / 32, 256, 0, stream>>>(xb, h0b, Wmx, bmx, Wmh, bmh, Wx,
                                                    m_ws, g1_ws);
  k_g2<<<4 * H_ / 32, 256, 0, stream>>>(m_ws, Wm, g2_ws);
  k_gates<<<(B_ * H_) / 256, 256, 0, stream>>>(g1_ws, g2_ws, bx, bm, c0, h_ws, Acat);
  k_attn_partial<<<B_ * NSPLIT, 256, 0, stream>>>(sv, h_ws, ctxp, Mp, Lp);
  k_attn_combine<<<B_, 256, 0, stream>>>(ctxp, Mp, Lp, Acat);
  k_logits<<<V_ / 64, 256, 0, stream>>>(Acat, Wout, bout, out);
}

// Round 4
// 524.009 us; speedup vs baseline: 1.1184x; 1.0900x over previous
//
#include <hip/hip_runtime.h>

// Problem dims
#define B_ 64
#define E_ 2048
#define H_ 1024
#define S_ 512
#define V_ 32000
#define NSPLIT 8
#define KT 128     // k-rows per staged tile (MLP gemms)
#define LDT 136    // padded LDS row length (bf16 elems), 272 B
#define KT2 64     // k-rows per staged tile (logits)
#define LDT2 72    // padded row length, 144 B

typedef __bf16 bf16x8 __attribute__((ext_vector_type(8)));
typedef float f32x4 __attribute__((ext_vector_type(4)));
typedef unsigned int u32;

__device__ __forceinline__ f32x4 mfma16(bf16x8 a, bf16x8 b, f32x4 c) {
  return __builtin_amdgcn_mfma_f32_16x16x32_bf16(a, b, c, 0, 0, 0);
}

__device__ __forceinline__ u32 packbf2(float lo, float hi) {
  union { __bf16 h[2]; u32 w; } u;
  u.h[0] = (__bf16)lo; u.h[1] = (__bf16)hi;
  return u.w;
}

// 8 consecutive fp32 -> bf16x8
__device__ __forceinline__ bf16x8 cvt8(const float* __restrict__ p) {
  f32x4 a = *(const f32x4*)p;
  f32x4 b = *(const f32x4*)(p + 4);
  bf16x8 r;
#pragma unroll
  for (int j = 0; j < 4; ++j) { r[j] = (__bf16)a[j]; r[4 + j] = (__bf16)b[j]; }
  return r;
}

// ---------------------------------------------------------------------------
// Kernel P: convert x (64x2048) and h0 (64x1024) fp32 -> bf16 workspace.
// ---------------------------------------------------------------------------
__global__ __launch_bounds__(256) void k_prep(
    const float* __restrict__ x, const float* __restrict__ h0,
    __bf16* __restrict__ xb, __bf16* __restrict__ h0b) {
  int idx = (blockIdx.x * 256 + threadIdx.x) * 8;
  const float* src;
  __bf16* dst;
  if (idx < B_ * E_) { src = x + idx; dst = xb + idx; }
  else { int j = idx - B_ * E_; src = h0 + j; dst = h0b + j; }
  bf16x8 v = cvt8(src);
  *(bf16x8*)dst = v;
}

// ---------------------------------------------------------------------------
// gemm16: C[64 x 16] += A[64 x K](bf16) @ B[K x 16](fp32 strip).
// K-tile = 128 rows. A staged row-major in LDS (ds_read_b128 frags);
// B staged transposed [v][k] with packed b32 writes.
// Double-buffered LDS, 1-deep register prefetch, ONE barrier per tile.
// NT must be even (buffer parity across calls). Wave w: rows w*16..+15.
// ---------------------------------------------------------------------------
__device__ __forceinline__ void gemm16(
    const __bf16* __restrict__ A, int lda,
    const float* __restrict__ Bg, int ldb, int K,
    __bf16 (*At)[64][LDT], __bf16 (*Bt)[16][LDT], f32x4& acc) {
  const int tid = threadIdx.x;
  const int wave = tid >> 6, lane = tid & 63;
  const int mi = lane & 15, ki = (lane >> 4) * 8;
  // B loader: 16 cols x 128 rows; thread covers rows bsk,bsk+1 at cols bsv..+3
  const int bsv = (tid & 3) * 4;
  const int bsk = (tid >> 2) * 2;
  // A loader: 64 rows x 128 elems; thread covers row ar, elems ac..ac+31
  const int ar = tid >> 2;
  const int ac = (tid & 3) * 32;
  const int NT = K / KT;
  f32x4 pB0 = *(const f32x4*)(Bg + (size_t)bsk * ldb + bsv);
  f32x4 pB1 = *(const f32x4*)(Bg + (size_t)(bsk + 1) * ldb + bsv);
  bf16x8 pA[4];
#pragma unroll
  for (int j = 0; j < 4; ++j)
    pA[j] = *(const bf16x8*)(A + (size_t)ar * lda + ac + j * 8);
  for (int t = 0; t < NT; ++t) {
    __bf16(*LB)[LDT] = Bt[t & 1];
    __bf16(*LA)[LDT] = At[t & 1];
    u32* BW = (u32*)&LB[0][0];
#pragma unroll
    for (int i = 0; i < 4; ++i)
      BW[(bsv + i) * (LDT / 2) + (bsk >> 1)] = packbf2(pB0[i], pB1[i]);
#pragma unroll
    for (int j = 0; j < 4; ++j)
      *(bf16x8*)(&LA[ar][ac + j * 8]) = pA[j];
    __syncthreads();
    if (t + 1 < NT) {
      const float* nB = Bg + (size_t)(t + 1) * KT * ldb;
      pB0 = *(const f32x4*)(nB + (size_t)bsk * ldb + bsv);
      pB1 = *(const f32x4*)(nB + (size_t)(bsk + 1) * ldb + bsv);
      const __bf16* nA = A + (size_t)(t + 1) * KT;
#pragma unroll
      for (int j = 0; j < 4; ++j)
        pA[j] = *(const bf16x8*)(nA + (size_t)ar * lda + ac + j * 8);
    }
#pragma unroll
    for (int kk = 0; kk < 4; ++kk) {
      bf16x8 bfrag = *(const bf16x8*)(&LB[mi][kk * 32 + ki]);
      bf16x8 afrag = *(const bf16x8*)(&LA[wave * 16 + mi][kk * 32 + ki]);
      acc = mfma16(afrag, bfrag, acc);
    }
  }
}

// ---------------------------------------------------------------------------
// Kernel A: blocks [0,64): m = (x@Wmx+bmx)*(h0@Wmh+bmh) -> bf16 ws
//           blocks [64,320): g1 = x@Wx (raw) -> fp32 ws
// ---------------------------------------------------------------------------
__global__ __launch_bounds__(256) void k_m_g1(
    const __bf16* __restrict__ xb, const __bf16* __restrict__ h0b,
    const float* __restrict__ Wmx, const float* __restrict__ bmx,
    const float* __restrict__ Wmh, const float* __restrict__ bmh,
    const float* __restrict__ Wx,
    __bf16* __restrict__ m_out, float* __restrict__ g1) {
  __shared__ __bf16 At[2][64][LDT];   // 34 KB
  __shared__ __bf16 Bt[2][16][LDT];   // 8.5 KB
  const int tid = threadIdx.x;
  const int wave = tid >> 6, lane = tid & 63;
  const int mi = lane & 15;
  const int blk = blockIdx.x;
  if (blk < H_ / 16) {
    const int v0 = blk * 16;
    f32x4 amx = {0.f, 0.f, 0.f, 0.f}, amh = {0.f, 0.f, 0.f, 0.f};
    gemm16(xb, E_, Wmx + v0, H_, E_, At, Bt, amx);
    gemm16(h0b, H_, Wmh + v0, H_, H_, At, Bt, amh);
    const int col = v0 + mi;
    const float bxv = bmx[col], bhv = bmh[col];
#pragma unroll
    for (int r = 0; r < 4; ++r) {
      int row = wave * 16 + (lane >> 4) * 4 + r;
      m_out[(size_t)row * H_ + col] = (__bf16)((amx[r] + bxv) * (amh[r] + bhv));
    }
  } else {
    const int v0 = (blk - H_ / 16) * 16;
    f32x4 acc = {0.f, 0.f, 0.f, 0.f};
    gemm16(xb, E_, Wx + v0, 4 * H_, E_, At, Bt, acc);
    const int col = v0 + mi;
#pragma unroll
    for (int r = 0; r < 4; ++r) {
      int row = wave * 16 + (lane >> 4) * 4 + r;
      g1[(size_t)row * 4 * H_ + col] = acc[r];
    }
  }
}

// ---------------------------------------------------------------------------
// Kernel C: g2 = m@Wm -> fp32 ws. 256 blocks (16-col strips of 4096).
// ---------------------------------------------------------------------------
__global__ __launch_bounds__(256) void k_g2(
    const __bf16* __restrict__ m_in, const float* __restrict__ Wm,
    float* __restrict__ g2) {
  __shared__ __bf16 At[2][64][LDT];
  __shared__ __bf16 Bt[2][16][LDT];
  const int tid = threadIdx.x;
  const int wave = tid >> 6, lane = tid & 63;
  const int mi = lane & 15;
  const int v0 = blockIdx.x * 16;
  f32x4 acc = {0.f, 0.f, 0.f, 0.f};
  gemm16(m_in, H_, Wm + v0, 4 * H_, H_, At, Bt, acc);
  const int col = v0 + mi;
#pragma unroll
  for (int r = 0; r < 4; ++r) {
    int row = wave * 16 + (lane >> 4) * 4 + r;
    g2[(size_t)row * 4 * H_ + col] = acc[r];
  }
}

// ---------------------------------------------------------------------------
// Kernel D: gates -> h (fp32) and Acat[:, 0:H] (bf16).
// ---------------------------------------------------------------------------
__global__ __launch_bounds__(256) void k_gates(
    const float* __restrict__ g1, const float* __restrict__ g2,
    const float* __restrict__ bx, const float* __restrict__ bm,
    const float* __restrict__ c0,
    float* __restrict__ h_f32, __bf16* __restrict__ Acat) {
  const int idx = blockIdx.x * blockDim.x + threadIdx.x;
  const int b = idx >> 10, j = idx & (H_ - 1);
  const size_t base = (size_t)b * 4 * H_ + j;
  float gf = g1[base] + g2[base] + bx[j] + bm[j];
  float gi = g1[base + H_] + g2[base + H_] + bx[j + H_] + bm[j + H_];
  float go = g1[base + 2 * H_] + g2[base + 2 * H_] + bx[j + 2 * H_] + bm[j + 2 * H_];
  float gc = g1[base + 3 * H_] + g2[base + 3 * H_] + bx[j + 3 * H_] + bm[j + 3 * H_];
  float f = 1.f / (1.f + __expf(-gf));
  float i = 1.f / (1.f + __expf(-gi));
  float o = 1.f / (1.f + __expf(-go));
  float ct = tanhf(gc);
  float c = f * c0[(size_t)b * H_ + j] + i * ct;
  float h = o * tanhf(c);
  h_f32[(size_t)b * H_ + j] = h;
  Acat[(size_t)b * 2 * H_ + j] = (__bf16)h;
}

// ---------------------------------------------------------------------------
// Online-softmax accumulate step (replaces the old STEP macro).
// ---------------------------------------------------------------------------
__device__ __forceinline__ void sm_step(float score, const f32x4& cv,
                                        float& M, float& L, float* cx) {
  float nM = fmaxf(M, score);
  float al = __expf(M - nM);
  float w = __expf(score - nM);
  L = L * al + w;
#pragma unroll
  for (int i = 0; i < 4; ++i) cx[i] = cx[i] * al + w * cv[i];
  M = nM;
}

// ---------------------------------------------------------------------------
// Kernel E: flash-style attention partials. Grid = 64*NSPLIT = 512 blocks.
// Software-pipelined: next 4 rows issued before reduce/softmax of current 4.
// ---------------------------------------------------------------------------
__global__ __launch_bounds__(256) void k_attn_partial(
    const float* __restrict__ sv, const float* __restrict__ h_f32,
    float* __restrict__ ctxp, float* __restrict__ Mp, float* __restrict__ Lp) {
  const int b = blockIdx.x >> 3, split = blockIdx.x & (NSPLIT - 1);
  const int t = threadIdx.x;
  const int d0 = t * 4;
  float hr[4];
#pragma unroll
  for (int i = 0; i < 4; ++i) hr[i] = h_f32[(size_t)b * H_ + d0 + i];
  float M = -1e30f, L = 0.f;
  float cx[4] = {0.f, 0.f, 0.f, 0.f};
  __shared__ float red[2][4][4];
  const int SB = S_ / NSPLIT;  // 64
  const float* svb = sv + ((size_t)b * S_ + (size_t)split * SB) * H_;
  f32x4 n0 = *(const f32x4*)(svb + (size_t)0 * H_ + d0);
  f32x4 n1 = *(const f32x4*)(svb + (size_t)1 * H_ + d0);
  f32x4 n2 = *(const f32x4*)(svb + (size_t)2 * H_ + d0);
  f32x4 n3 = *(const f32x4*)(svb + (size_t)3 * H_ + d0);
  for (int s4 = 0; s4 < SB; s4 += 4) {
    f32x4 c0v = n0, c1v = n1, c2v = n2, c3v = n3;
    if (s4 + 4 < SB) {
      const float* p = svb + (size_t)(s4 + 4) * H_ + d0;
      n0 = *(const f32x4*)(p);
      n1 = *(const f32x4*)(p + H_);
      n2 = *(const f32x4*)(p + 2 * H_);
      n3 = *(const f32x4*)(p + 3 * H_);
    }
    float part[4];
    part[0] = hr[0] * c0v[0] + hr[1] * c0v[1] + hr[2] * c0v[2] + hr[3] * c0v[3];
    part[1] = hr[0] * c1v[0] + hr[1] * c1v[1] + hr[2] * c1v[2] + hr[3] * c1v[3];
    part[2] = hr[0] * c2v[0] + hr[1] * c2v[1] + hr[2] * c2v[2] + hr[3] * c2v[3];
    part[3] = hr[0] * c3v[0] + hr[1] * c3v[1] + hr[2] * c3v[2] + hr[3] * c3v[3];
#pragma unroll
    for (int ss = 0; ss < 4; ++ss)
#pragma unroll
      for (int off = 32; off > 0; off >>= 1) part[ss] += __shfl_xor(part[ss], off);
    const int wv = t >> 6, ln = t & 63;
    const int buf = (s4 >> 2) & 1;
    if (ln == 0) {
#pragma unroll
      for (int ss = 0; ss < 4; ++ss) red[buf][wv][ss] = part[ss];
    }
    __syncthreads();
    sm_step(red[buf][0][0] + red[buf][1][0] + red[buf][2][0] + red[buf][3][0], c0v, M, L, cx);
    sm_step(red[buf][0][1] + red[buf][1][1] + red[buf][2][1] + red[buf][3][1], c1v, M, L, cx);
    sm_step(red[buf][0][2] + red[buf][1][2] + red[buf][2][2] + red[buf][3][2], c2v, M, L, cx);
    sm_step(red[buf][0][3] + red[buf][1][3] + red[buf][2][3] + red[buf][3][3], c3v, M, L, cx);
  }
  const int p = b * NSPLIT + split;
#pragma unroll
  for (int i = 0; i < 4; ++i) ctxp[(size_t)p * H_ + d0 + i] = cx[i];
  if (t == 0) { Mp[p] = M; Lp[p] = L; }
}

// ---------------------------------------------------------------------------
// Kernel F: combine partials -> context -> Acat[:, H:2H] (bf16). 64 blocks.
// ---------------------------------------------------------------------------
__global__ __launch_bounds__(256) void k_attn_combine(
    const float* __restrict__ ctxp, const float* __restrict__ Mp,
    const float* __restrict__ Lp, __bf16* __restrict__ Acat) {
  const int b = blockIdx.x;
  const int t = threadIdx.x;
  const int d0 = t * 4;
  float gM = -1e30f;
#pragma unroll
  for (int s = 0; s < NSPLIT; ++s) gM = fmaxf(gM, Mp[b * NSPLIT + s]);
  float w[NSPLIT];
  float T = 0.f;
#pragma unroll
  for (int s = 0; s < NSPLIT; ++s) {
    w[s] = __expf(Mp[b * NSPLIT + s] - gM);
    T += w[s] * Lp[b * NSPLIT + s];
  }
  const float inv = 1.f / T;
  float cx[4] = {0.f, 0.f, 0.f, 0.f};
#pragma unroll
  for (int s = 0; s < NSPLIT; ++s) {
#pragma unroll
    for (int i = 0; i < 4; ++i) cx[i] += w[s] * ctxp[(size_t)(b * NSPLIT + s) * H_ + d0 + i];
  }
#pragma unroll
  for (int i = 0; i < 4; ++i)
    Acat[(size_t)b * 2 * H_ + H_ + d0 + i] = (__bf16)(cx[i] * inv);
}

// ---------------------------------------------------------------------------
// Kernel G: logits = Acat@Wout + bout. 500 blocks x 256, 64-col strips.
// K-tile 64; A (Acat) + B (Wout, transposed) staged in LDS (36 KB total ->
// 4 blocks/CU), double-buffered, 1-deep register prefetch, 1 barrier/tile.
// ---------------------------------------------------------------------------
__global__ __launch_bounds__(256) void k_logits(
    const __bf16* __restrict__ Acat, const float* __restrict__ Wout,
    const float* __restrict__ bout, float* __restrict__ out) {
  __shared__ __bf16 At[2][64][LDT2];  // 18 KB
  __shared__ __bf16 Bt[2][64][LDT2];  // 18 KB
  const int tid = threadIdx.x;
  const int wave = tid >> 6, lane = tid & 63;
  const int mi = lane & 15, ki = (lane >> 4) * 8;
  const int v0 = blockIdx.x * 64;
  // B loader: per tile 64 k-rows x 64 cols; thread: cols bsv..+3,
  // rows {bsk, bsk+1, bsk+32, bsk+33}
  const int bsv = (tid & 15) * 4;
  const int bsk = (tid >> 4) * 2;
  // A loader: row ar (0..63), elems ac..ac+15
  const int ar = tid >> 2;
  const int ac = (tid & 3) * 16;
  const float* Bg = Wout + v0;
  const int NT = 2 * H_ / KT2;  // 32
  f32x4 pB[2][2];
#pragma unroll
  for (int r = 0; r < 2; ++r)
#pragma unroll
    for (int p = 0; p < 2; ++p)
      pB[r][p] = *(const f32x4*)(Bg + (size_t)(bsk + 32 * r + p) * V_ + bsv);
  bf16x8 pA[2];
#pragma unroll
  for (int j = 0; j < 2; ++j)
    pA[j] = *(const bf16x8*)(Acat + (size_t)ar * 2 * H_ + ac + j * 8);
  f32x4 acc[4] = {};
  for (int t = 0; t < NT; ++t) {
    __bf16(*LB)[LDT2] = Bt[t & 1];
    __bf16(*LA)[LDT2] = At[t & 1];
    u32* BW = (u32*)&LB[0][0];
#pragma unroll
    for (int r = 0; r < 2; ++r)
#pragma unroll
      for (int i = 0; i < 4; ++i)
        BW[(bsv + i) * (LDT2 / 2) + ((bsk + 32 * r) >> 1)] =
            packbf2(pB[r][0][i], pB[r][1][i]);
#pragma unroll
    for (int j = 0; j < 2; ++j)
      *(bf16x8*)(&LA[ar][ac + j * 8]) = pA[j];
    __syncthreads();
    if (t + 1 < NT) {
      const float* nB = Bg + (size_t)(t + 1) * KT2 * V_;
#pragma unroll
      for (int r = 0; r < 2; ++r)
#pragma unroll
        for (int p = 0; p < 2; ++p)
          pB[r][p] = *(const f32x4*)(nB + (size_t)(bsk + 32 * r + p) * V_ + bsv);
      const __bf16* nA = Acat + (size_t)(t + 1) * KT2;
#pragma unroll
      for (int j = 0; j < 2; ++j)
        pA[j] = *(const bf16x8*)(nA + (size_t)ar * 2 * H_ + ac + j * 8);
    }
#pragma unroll
    for (int kk = 0; kk < 2; ++kk) {
      bf16x8 bfrag = *(const bf16x8*)(&LB[wave * 16 + mi][kk * 32 + ki]);
#pragma unroll
      for (int mt = 0; mt < 4; ++mt) {
        bf16x8 afrag = *(const bf16x8*)(&LA[mt * 16 + mi][kk * 32 + ki]);
        acc[mt] = mfma16(afrag, bfrag, acc[mt]);
      }
    }
  }
  const int col = v0 + wave * 16 + mi;
  const float bo = bout[col];
#pragma unroll
  for (int mt = 0; mt < 4; ++mt)
#pragma unroll
    for (int r = 0; r < 4; ++r) {
      int row = mt * 16 + (lane >> 4) * 4 + r;
      out[(size_t)row * V_ + col] = acc[mt][r] + bo;
    }
}

// ---------------------------------------------------------------------------
extern "C" void kernel_launch(void* const* d_in, const int* in_sizes, int n_in,
                              void* d_out, int out_size, void* d_ws, size_t ws_size,
                              hipStream_t stream) {
  const float* x    = (const float*)d_in[0];
  const float* h0   = (const float*)d_in[1];
  const float* c0   = (const float*)d_in[2];
  const float* sv   = (const float*)d_in[3];
  const float* Wmx  = (const float*)d_in[4];
  const float* bmx  = (const float*)d_in[5];
  const float* Wmh  = (const float*)d_in[6];
  const float* bmh  = (const float*)d_in[7];
  const float* Wx   = (const float*)d_in[8];
  const float* bx   = (const float*)d_in[9];
  const float* Wm   = (const float*)d_in[10];
  const float* bm   = (const float*)d_in[11];
  const float* Wout = (const float*)d_in[12];
  const float* bout = (const float*)d_in[13];
  float* out = (float*)d_out;

  char* ws = (char*)d_ws;
  size_t off = 0;
  __bf16* m_ws = (__bf16*)(ws + off); off += (size_t)B_ * H_ * 2;              // 128KB
  float* g1_ws = (float*)(ws + off);  off += (size_t)B_ * 4 * H_ * 4;          // 1MB
  float* g2_ws = (float*)(ws + off);  off += (size_t)B_ * 4 * H_ * 4;          // 1MB
  float* h_ws  = (float*)(ws + off);  off += (size_t)B_ * H_ * 4;              // 256KB
  __bf16* Acat = (__bf16*)(ws + off); off += (size_t)B_ * 2 * H_ * 2;          // 256KB
  float* ctxp  = (float*)(ws + off);  off += (size_t)B_ * NSPLIT * H_ * 4;     // 2MB
  float* Mp    = (float*)(ws + off);  off += (size_t)B_ * NSPLIT * 4;
  float* Lp    = (float*)(ws + off);  off += (size_t)B_ * NSPLIT * 4;
  __bf16* xb   = (__bf16*)(ws + off); off += (size_t)B_ * E_ * 2;              // 256KB
  __bf16* h0b  = (__bf16*)(ws + off); off += (size_t)B_ * H_ * 2;              // 128KB

  k_prep<<<(B_ * E_ + B_ * H_) / (256 * 8), 256, 0, stream>>>(x, h0, xb, h0b);
  k_m_g1<<<H_ / 16 + 4 * H_ / 16, 256, 0, stream>>>(xb, h0b, Wmx, bmx, Wmh, bmh, Wx,
                                                    m_ws, g1_ws);
  k_g2<<<4 * H_ / 16, 256, 0, stream>>>(m_ws, Wm, g2_ws);
  k_gates<<<(B_ * H_) / 256, 256, 0, stream>>>(g1_ws, g2_ws, bx, bm, c0, h_ws, Acat);
  k_attn_partial<<<B_ * NSPLIT, 256, 0, stream>>>(sv, h_ws, ctxp, Mp, Lp);
  k_attn_combine<<<B_, 256, 0, stream>>>(ctxp, Mp, Lp, Acat);
  k_logits<<<V_ / 64, 256, 0, stream>>>(Acat, Wout, bout, out);
}